// Round 3
// baseline (439.928 us; speedup 1.0000x reference)
//
#include <hip/hip_runtime.h>

// Problem constants (from reference: B,C,H,W = 8,8,512,512)
constexpr int Bn = 8, Cn = 8, Hn = 512, Wn = 512;
constexpr int HW = Hn * Wn;            // 262144
constexpr int NPIX = Bn * HW;          // 2,097,152  (= N1, the [B,1,H,W] mean count)
constexpr int NTHREADS = NPIX / 4;     // each thread does 4 consecutive pixels
constexpr int BLOCK = 256;
constexpr int NBLK = NTHREADS / BLOCK; // 2048

__device__ __forceinline__ float sigf(float x) {
    return 1.0f / (1.0f + __expf(-x));
}

// Per-level contribution for 4 consecutive pixels. o points at (b, c=0, h, w4).
// s[c][j], neighbors etc. are freshly computed per level; acc accumulates
// dw*edge_term + (cw/8)*sum_c con_term + (bw/8)*sum_c vote_term.
__device__ __forceinline__ void level_contrib(
    const float* __restrict__ o,
    const float ct[8][4], const float tj[4], const float edge[4],
    bool hasL, bool hasR, bool hasU, bool hasD,
    float dw, float cw8, float bw8, float& acc)
{
    // ---- center: sigmoid + con-BCE (log(sig)= -L, log(1-sig) = -x-L, L=log(1+e^-x))
    float s[8][4];
    float con_sum[4] = {0.f, 0.f, 0.f, 0.f};
    #pragma unroll
    for (int c = 0; c < 8; ++c) {
        float4 v = *reinterpret_cast<const float4*>(o + c * HW);
        float xs[4] = {v.x, v.y, v.z, v.w};
        #pragma unroll
        for (int j = 0; j < 4; ++j) {
            float x = xs[j];
            float e = __expf(-x);
            s[c][j] = 1.0f / (1.0f + e);
            float L = __logf(1.0f + e);
            float lg = (ct[c][j] != 0.f) ? (-L) : (-x - L);
            con_sum[j] += fmaxf(lg, -100.f);
        }
    }

    // ---- neighbors (post-sigmoid values; zero outside the image)
    float n4s[4], n3s[4], n6s[4], n1s[4], n5s[4], n2s[4], n7s[4], n0s[4];

    // n4: c4 at (h, w-1): j>=1 reuse center sigmoids
    n4s[0] = hasL ? sigf(o[4 * HW - 1]) : 0.f;
    n4s[1] = s[4][0]; n4s[2] = s[4][1]; n4s[3] = s[4][2];
    // n3: c3 at (h, w+1)
    n3s[0] = s[3][1]; n3s[1] = s[3][2]; n3s[2] = s[3][3];
    n3s[3] = hasR ? sigf(o[3 * HW + 4]) : 0.f;

    if (hasU) {
        float4 v6 = *reinterpret_cast<const float4*>(o + 6 * HW - Wn);
        float4 v5 = *reinterpret_cast<const float4*>(o + 5 * HW - Wn);
        float4 v7 = *reinterpret_cast<const float4*>(o + 7 * HW - Wn);
        // n6: c6 at (h-1, w)
        n6s[0] = sigf(v6.x); n6s[1] = sigf(v6.y); n6s[2] = sigf(v6.z); n6s[3] = sigf(v6.w);
        // n5: c5 at (h-1, w+1)
        n5s[0] = sigf(v5.y); n5s[1] = sigf(v5.z); n5s[2] = sigf(v5.w);
        n5s[3] = hasR ? sigf(o[5 * HW - Wn + 4]) : 0.f;
        // n7: c7 at (h-1, w-1)
        n7s[0] = hasL ? sigf(o[7 * HW - Wn - 1]) : 0.f;
        n7s[1] = sigf(v7.x); n7s[2] = sigf(v7.y); n7s[3] = sigf(v7.z);
    } else {
        #pragma unroll
        for (int j = 0; j < 4; ++j) { n6s[j] = 0.f; n5s[j] = 0.f; n7s[j] = 0.f; }
    }

    if (hasD) {
        float4 v1 = *reinterpret_cast<const float4*>(o + 1 * HW + Wn);
        float4 v2 = *reinterpret_cast<const float4*>(o + 2 * HW + Wn);
        float4 v0 = *reinterpret_cast<const float4*>(o + 0 * HW + Wn);
        // n1: c1 at (h+1, w)
        n1s[0] = sigf(v1.x); n1s[1] = sigf(v1.y); n1s[2] = sigf(v1.z); n1s[3] = sigf(v1.w);
        // n2: c2 at (h+1, w-1)
        n2s[0] = hasL ? sigf(o[2 * HW + Wn - 1]) : 0.f;
        n2s[1] = sigf(v2.x); n2s[2] = sigf(v2.y); n2s[3] = sigf(v2.z);
        // n0: c0 at (h+1, w+1)
        n0s[0] = sigf(v0.y); n0s[1] = sigf(v0.z); n0s[2] = sigf(v0.w);
        n0s[3] = hasR ? sigf(o[0 * HW + Wn + 4]) : 0.f;
    } else {
        #pragma unroll
        for (int j = 0; j < 4; ++j) { n1s[j] = 0.f; n2s[j] = 0.f; n0s[j] = 0.f; }
    }

    // ---- votes, vote-BCE, edge-BCE
    #pragma unroll
    for (int j = 0; j < 4; ++j) {
        float a1 = s[3][j] * n4s[j];
        float a2 = s[4][j] * n3s[j];
        float a3 = s[1][j] * n6s[j];
        float a4 = s[6][j] * n1s[j];
        float a5 = s[2][j] * n5s[j];
        float a6 = s[5][j] * n2s[j];
        float a7 = s[0][j] * n7s[j];
        float a8 = s[7][j] * n0s[j];
        // vote_out channel order: [a7,a3,a5,a1,a2,a6,a4,a8]
        float vt[8] = {a7, a3, a5, a1, a2, a6, a4, a8};
        float vsum = 0.f, vmin = vt[0], vs = 0.f;
        #pragma unroll
        for (int c = 0; c < 8; ++c) {
            float a = vt[c];
            vsum += a;
            vmin = fminf(vmin, a);
            float arg = (ct[c][j] != 0.f) ? a : (1.0f - a);
            vs += fmaxf(__logf(arg), -100.f);   // __logf(0) = -inf -> clamped to -100
        }
        float glo = vsum * 0.125f;
        float dec = (edge[j] != 0.f) ? (1.0f - vmin) : glo;
        float earg = (tj[j] != 0.f) ? dec : (1.0f - dec);
        float et = fmaxf(__logf(earg), -100.f);
        acc += dw * et + cw8 * con_sum[j] + bw8 * vs;
    }
}

__global__ __launch_bounds__(BLOCK) void bicon_main(
    const float* __restrict__ O0, const float* __restrict__ O1,
    const float* __restrict__ O2, const float* __restrict__ O3,
    const float* __restrict__ TGT, const float* __restrict__ CT,
    double* __restrict__ partial)
{
    const int t = blockIdx.x * BLOCK + threadIdx.x;
    const int b = t / (HW / 4);
    const int rem = t - b * (HW / 4);
    const int h = rem / (Wn / 4);
    const int w4 = (rem - h * (Wn / 4)) * 4;

    const int cbase = b * Cn * HW + h * Wn + w4;  // (b, c=0, h, w4); channel stride HW

    // con_target (8 channels) + target
    float ct[8][4];
    #pragma unroll
    for (int c = 0; c < 8; ++c) {
        float4 v = *reinterpret_cast<const float4*>(CT + cbase + c * HW);
        ct[c][0] = v.x; ct[c][1] = v.y; ct[c][2] = v.z; ct[c][3] = v.w;
    }
    float4 tv = *reinterpret_cast<const float4*>(TGT + b * HW + h * Wn + w4);
    float tj[4] = {tv.x, tv.y, tv.z, tv.w};

    float edge[4];
    #pragma unroll
    for (int j = 0; j < 4; ++j) {
        float sc = 0.f;
        #pragma unroll
        for (int c = 0; c < 8; ++c) sc += ct[c][j];
        edge[j] = (sc > 0.f && sc < 8.f) ? 1.f : 0.f;
    }

    const bool hasL = (w4 > 0), hasR = (w4 + 4 < Wn);
    const bool hasU = (h > 0), hasD = (h + 1 < Hn);

    float acc = 0.f;
    // de_w = {1.0,0.8,0.6,0.4}; con_w/8; bi_w/8
    level_contrib(O0 + cbase, ct, tj, edge, hasL, hasR, hasU, hasD, 1.0f,  0.8f  / 8.f, 0.2f  / 8.f, acc);
    level_contrib(O1 + cbase, ct, tj, edge, hasL, hasR, hasU, hasD, 0.8f,  0.64f / 8.f, 0.16f / 8.f, acc);
    level_contrib(O2 + cbase, ct, tj, edge, hasL, hasR, hasU, hasD, 0.6f,  0.48f / 8.f, 0.12f / 8.f, acc);
    level_contrib(O3 + cbase, ct, tj, edge, hasL, hasR, hasU, hasD, 0.4f,  0.32f / 8.f, 0.08f / 8.f, acc);

    // block reduction: wave shuffle -> LDS -> one double partial per block
    #pragma unroll
    for (int off = 32; off; off >>= 1) acc += __shfl_down(acc, off, 64);
    __shared__ float sm[BLOCK / 64];
    const int lane = threadIdx.x & 63, wv = threadIdx.x >> 6;
    if (lane == 0) sm[wv] = acc;
    __syncthreads();
    if (threadIdx.x == 0) {
        float sblk = sm[0] + sm[1] + sm[2] + sm[3];
        partial[blockIdx.x] = (double)sblk;
    }
}

__global__ __launch_bounds__(256) void bicon_fin(
    const double* __restrict__ partial, float* __restrict__ out)
{
    double a = 0.0;
    for (int i = threadIdx.x; i < NBLK; i += 256) a += partial[i];
    #pragma unroll
    for (int off = 32; off; off >>= 1) a += __shfl_down(a, off, 64);
    __shared__ double sh[4];
    const int lane = threadIdx.x & 63, wv = threadIdx.x >> 6;
    if (lane == 0) sh[wv] = a;
    __syncthreads();
    if (threadIdx.x == 0) {
        double s = sh[0] + sh[1] + sh[2] + sh[3];
        out[0] = (float)(-s / (double)NPIX);
    }
}

extern "C" void kernel_launch(void* const* d_in, const int* in_sizes, int n_in,
                              void* d_out, int out_size, void* d_ws, size_t ws_size,
                              hipStream_t stream) {
    const float* o2  = (const float*)d_in[0];
    const float* o3  = (const float*)d_in[1];
    const float* o4  = (const float*)d_in[2];
    const float* o5  = (const float*)d_in[3];
    const float* tgt = (const float*)d_in[4];
    const float* ct  = (const float*)d_in[5];
    double* partial = (double*)d_ws;   // NBLK doubles = 16 KiB; fully overwritten every call

    bicon_main<<<NBLK, BLOCK, 0, stream>>>(o2, o3, o4, o5, tgt, ct, partial);
    bicon_fin<<<1, 256, 0, stream>>>(partial, (float*)d_out);
}

// Round 7
// 313.248 us; speedup vs baseline: 1.4044x; 1.4044x over previous
//
#include <hip/hip_runtime.h>

// Problem constants (B,C,H,W = 8,8,512,512)
constexpr int Bn = 8, Cn = 8, Hn = 512, Wn = 512;
constexpr int HW = Hn * Wn;              // 262144
constexpr int NPIX = Bn * HW;            // 2,097,152
constexpr int BLOCK = 256;
constexpr int NBLK = NPIX / 2 / BLOCK;   // 4096 (one block = one image row, 2 px/thread)

__device__ __forceinline__ float rcpf(float x) { return __builtin_amdgcn_rcpf(x); }

// Guarded loads: invalid -> x = -1e30 so exp(-x) = +inf so vote product = rcp(inf) = 0,
// exactly matching the reference's zero-padded shifts. Clamped address stays in-bounds.
__device__ __forceinline__ float ldg1(const float* __restrict__ p, int off, bool v) {
    float x = p[v ? off : 0];
    return v ? x : -1e30f;
}
__device__ __forceinline__ float2 ldg2(const float* __restrict__ p, int off, bool v) {
    float2 r = *reinterpret_cast<const float2*>(p + (v ? off : 0));
    if (!v) { r.x = -1e30f; r.y = -1e30f; }
    return r;
}

// One level (one of out2..out5) for 2 adjacent pixels (w2, w2+1).
// o points at (b, c=0, h, w2). ctm: bits 0..7 = con_target px0, bits 8..15 = px1.
__device__ __forceinline__ void level(
    const float* __restrict__ o, unsigned ctm,
    bool e0b, bool e1b, bool t0b, bool t1b,
    bool hasL, bool hasR, bool hasU, bool hasD,
    float dw, float cw8, float bw8, float& acc)
{
    // ---- center: e = exp(-x); con-BCE via log(sig) = -L, log(1-sig) = -x-L, L = log(1+e)
    float ec0[8], ec1[8];
    float con0 = 0.f, con1 = 0.f;
    #pragma unroll
    for (int c = 0; c < 8; ++c) {
        float2 v = *reinterpret_cast<const float2*>(o + c * HW);
        float e0 = __expf(-v.x), e1 = __expf(-v.y);
        ec0[c] = e0; ec1[c] = e1;
        float L0 = __logf(1.f + e0), L1 = __logf(1.f + e1);
        con0 -= L0 + (((ctm >> c) & 1u) ? 0.f : v.x);
        con1 -= L1 + (((ctm >> (c + 8)) & 1u) ? 0.f : v.y);
    }

    // ---- neighbor e by direction d (en[d] = e of channel-d value at its shifted source)
    float en0[8], en1[8];
    // n4: c4 at (h, w-1)
    en0[4] = __expf(-ldg1(o, 4 * HW - 1, hasL));
    en1[4] = ec0[4];
    // n3: c3 at (h, w+1)
    en0[3] = ec1[3];
    en1[3] = __expf(-ldg1(o, 3 * HW + 2, hasR));
    // row h-1: c6 (w), c5 (w+1), c7 (w-1)
    {
        float2 v6 = ldg2(o, 6 * HW - Wn, hasU);
        en0[6] = __expf(-v6.x); en1[6] = __expf(-v6.y);
        float2 v5 = ldg2(o, 5 * HW - Wn, hasU);
        en0[5] = __expf(-v5.y);
        en1[5] = __expf(-ldg1(o, 5 * HW - Wn + 2, hasU && hasR));
        float2 v7 = ldg2(o, 7 * HW - Wn, hasU);
        en0[7] = __expf(-ldg1(o, 7 * HW - Wn - 1, hasU && hasL));
        en1[7] = __expf(-v7.x);
    }
    // row h+1: c1 (w), c2 (w-1), c0 (w+1)
    {
        float2 v1 = ldg2(o, 1 * HW + Wn, hasD);
        en0[1] = __expf(-v1.x); en1[1] = __expf(-v1.y);
        float2 v2 = ldg2(o, 2 * HW + Wn, hasD);
        en0[2] = __expf(-ldg1(o, 2 * HW + Wn - 1, hasD && hasL));
        en1[2] = __expf(-v2.x);
        float2 v0 = ldg2(o, 0 * HW + Wn, hasD);
        en0[0] = __expf(-v0.y);
        en1[0] = __expf(-ldg1(o, 0 * HW + Wn + 2, hasD && hasR));
    }

    // ---- votes: vote-channel k = center ch k * neighbor dir (7-k)
    //   a = sig_i*sig_j = rcp((1+e_i)(1+e_j)) = rcp(fma(e_i,e_j, 1+e_i+e_j))  [1 rcp, no div]
    float vs0 = 0.f, vsum0 = 0.f, vmin0 = 2.f;
    float vs1 = 0.f, vsum1 = 0.f, vmin1 = 2.f;
    #pragma unroll
    for (int k = 0; k < 8; ++k) {
        {
            float ek = ec0[k], en = en0[7 - k];
            float q = fmaf(ek, en, 1.f + ek + en);
            float a = rcpf(q);
            vsum0 += a; vmin0 = fminf(vmin0, a);
            float arg = ((ctm >> k) & 1u) ? a : (1.f - a);
            vs0 += fmaxf(__logf(arg), -100.f);
        }
        {
            float ek = ec1[k], en = en1[7 - k];
            float q = fmaf(ek, en, 1.f + ek + en);
            float a = rcpf(q);
            vsum1 += a; vmin1 = fminf(vmin1, a);
            float arg = ((ctm >> (k + 8)) & 1u) ? a : (1.f - a);
            vs1 += fmaxf(__logf(arg), -100.f);
        }
    }

    // ---- edge/decouple BCE
    float dec0 = e0b ? (1.f - vmin0) : (vsum0 * 0.125f);
    float dec1 = e1b ? (1.f - vmin1) : (vsum1 * 0.125f);
    float g0 = t0b ? dec0 : (1.f - dec0);
    float g1 = t1b ? dec1 : (1.f - dec1);
    acc += dw * (fmaxf(__logf(g0), -100.f) + fmaxf(__logf(g1), -100.f))
         + cw8 * (con0 + con1) + bw8 * (vs0 + vs1);
}

__global__ __launch_bounds__(BLOCK, 4) void bicon_main(
    const float* __restrict__ O0, const float* __restrict__ O1,
    const float* __restrict__ O2, const float* __restrict__ O3,
    const float* __restrict__ TGT, const float* __restrict__ CT,
    double* __restrict__ partial)
{
    const int blk = blockIdx.x;
    const int b = blk >> 9;            // 512 rows per image
    const int h = blk & 511;
    const int w2 = threadIdx.x << 1;   // 2 px per thread, one block = one row
    const int base = b * (Cn * HW) + h * Wn + w2;

    // con_target -> 16-bit mask (values are exact {0,1}); edge via popcount
    unsigned ctm = 0;
    #pragma unroll
    for (int c = 0; c < 8; ++c) {
        float2 v = *reinterpret_cast<const float2*>(CT + base + c * HW);
        ctm |= (v.x != 0.f ? 1u : 0u) << c;
        ctm |= (v.y != 0.f ? 1u : 0u) << (c + 8);
    }
    const int p0 = __popc(ctm & 0xFFu), p1 = __popc(ctm & 0xFF00u);
    const bool e0b = (p0 > 0) && (p0 < 8);
    const bool e1b = (p1 > 0) && (p1 < 8);
    float2 tv = *reinterpret_cast<const float2*>(TGT + b * HW + h * Wn + w2);
    const bool t0b = (tv.x != 0.f), t1b = (tv.y != 0.f);

    const bool hasL = (w2 > 0), hasR = (w2 + 2 < Wn);
    const bool hasU = (h > 0), hasD = (h + 1 < Hn);

    float acc = 0.f;
    level(O0 + base, ctm, e0b, e1b, t0b, t1b, hasL, hasR, hasU, hasD, 1.0f, 0.8f / 8.f, 0.2f / 8.f, acc);
    level(O1 + base, ctm, e0b, e1b, t0b, t1b, hasL, hasR, hasU, hasD, 0.8f, 0.64f / 8.f, 0.16f / 8.f, acc);
    level(O2 + base, ctm, e0b, e1b, t0b, t1b, hasL, hasR, hasU, hasD, 0.6f, 0.48f / 8.f, 0.12f / 8.f, acc);
    level(O3 + base, ctm, e0b, e1b, t0b, t1b, hasL, hasR, hasU, hasD, 0.4f, 0.32f / 8.f, 0.08f / 8.f, acc);

    // block reduction: wave shuffle -> LDS -> one double partial per block
    #pragma unroll
    for (int off = 32; off; off >>= 1) acc += __shfl_down(acc, off, 64);
    __shared__ float sm[BLOCK / 64];
    const int lane = threadIdx.x & 63, wv = threadIdx.x >> 6;
    if (lane == 0) sm[wv] = acc;
    __syncthreads();
    if (threadIdx.x == 0) {
        partial[blockIdx.x] = (double)(sm[0] + sm[1] + sm[2] + sm[3]);
    }
}

__global__ __launch_bounds__(256) void bicon_fin(
    const double* __restrict__ partial, float* __restrict__ out)
{
    double a = 0.0;
    for (int i = threadIdx.x; i < NBLK; i += 256) a += partial[i];
    #pragma unroll
    for (int off = 32; off; off >>= 1) a += __shfl_down(a, off, 64);
    __shared__ double sh[4];
    const int lane = threadIdx.x & 63, wv = threadIdx.x >> 6;
    if (lane == 0) sh[wv] = a;
    __syncthreads();
    if (threadIdx.x == 0) {
        out[0] = (float)(-(sh[0] + sh[1] + sh[2] + sh[3]) / (double)NPIX);
    }
}

extern "C" void kernel_launch(void* const* d_in, const int* in_sizes, int n_in,
                              void* d_out, int out_size, void* d_ws, size_t ws_size,
                              hipStream_t stream) {
    const float* o2  = (const float*)d_in[0];
    const float* o3  = (const float*)d_in[1];
    const float* o4  = (const float*)d_in[2];
    const float* o5  = (const float*)d_in[3];
    const float* tgt = (const float*)d_in[4];
    const float* ct  = (const float*)d_in[5];
    double* partial = (double*)d_ws;   // NBLK doubles = 32 KiB; fully rewritten every call

    bicon_main<<<NBLK, BLOCK, 0, stream>>>(o2, o3, o4, o5, tgt, ct, partial);
    bicon_fin<<<1, 256, 0, stream>>>(partial, (float*)d_out);
}